// Round 5
// baseline (44.673 us; speedup 1.0000x reference)
//
#include <hip/hip_runtime.h>

// out = w <= -0.5 ? -0.125 : (w > 0.5 ? 0.125 : 0)
// (clip to [-1,1] + nearest-of-{-8..8} with first-min tie-break -> {-1,0,1},
//  then /8. Tie at -0.5 -> -1, tie at +0.5 -> 0.)
//
// Round-5 probe: flip the cache policy. NT LOADS (stream input past
// L2/MALL) + REGULAR STORES (let the rewritten-every-replay output stay
// resident/dirty in Infinity Cache and absorb the HBM write traffic).
// If MALL is write-back and absorbs rewrites, per-replay HBM traffic
// halves to just the input read.

typedef float f32x4 __attribute__((ext_vector_type(4)));

__device__ __forceinline__ float quant1(float w) {
    return (w <= -0.5f) ? -0.125f : ((w > 0.5f) ? 0.125f : 0.0f);
}

__device__ __forceinline__ f32x4 quant4(f32x4 v) {
    f32x4 r;
    r.x = quant1(v.x);
    r.y = quant1(v.y);
    r.z = quant1(v.z);
    r.w = quant1(v.w);
    return r;
}

// Each block covers 1024 consecutive float4s. Thread t handles base+t,
// +256, +512, +768 -- wave-coalesced, 4 independent loads in flight.
__global__ __launch_bounds__(256) void hcq_v4_ntload(const f32x4* __restrict__ in,
                                                     f32x4* __restrict__ out) {
    long long base = (long long)blockIdx.x * 1024 + threadIdx.x;
    f32x4 v0 = __builtin_nontemporal_load(&in[base]);
    f32x4 v1 = __builtin_nontemporal_load(&in[base + 256]);
    f32x4 v2 = __builtin_nontemporal_load(&in[base + 512]);
    f32x4 v3 = __builtin_nontemporal_load(&in[base + 768]);
    out[base]       = quant4(v0);
    out[base + 256] = quant4(v1);
    out[base + 512] = quant4(v2);
    out[base + 768] = quant4(v3);
}

// Remainder: grid-stride over leftover elements (unused at 4096x8192 but
// kept for generality).
__global__ void hcq_tail(const float* __restrict__ in, float* __restrict__ out,
                         int n0, int n) {
    int i = n0 + blockIdx.x * blockDim.x + threadIdx.x;
    int stride = gridDim.x * blockDim.x;
    for (; i < n; i += stride) out[i] = quant1(in[i]);
}

extern "C" void kernel_launch(void* const* d_in, const int* in_sizes, int n_in,
                              void* d_out, int out_size, void* d_ws, size_t ws_size,
                              hipStream_t stream) {
    const float* w = (const float*)d_in[0];
    float* out = (float*)d_out;
    int n = in_sizes[0];

    int n4 = n / 4;
    int chunks = n4 / 1024;              // full 1024-float4 chunks
    if (chunks > 0) {
        hcq_v4_ntload<<<chunks, 256, 0, stream>>>((const f32x4*)w, (f32x4*)out);
    }
    int done = chunks * 1024 * 4;        // elements covered
    if (done < n) {
        int rem = n - done;
        int block = 256;
        int grid = (rem + block - 1) / block;
        if (grid > 1024) grid = 1024;
        hcq_tail<<<grid, block, 0, stream>>>(w, out, done, n);
    }
}

// Round 6
// 43.719 us; speedup vs baseline: 1.0218x; 1.0218x over previous
//
#include <hip/hip_runtime.h>

// out = w <= -0.5 ? -0.125 : (w > 0.5 ? 0.125 : 0)
// (clip to [-1,1] + nearest-of-{-8..8} with first-min tie-break -> {-1,0,1},
//  then /8. Tie at -0.5 -> -1, tie at +0.5 -> 0.)
//
// FINAL (round-4 best variant, 43.7 us = 97.6% of the 6.29 TB/s measured
// mixed-traffic HBM ceiling on 268 MB irreducible traffic):
//  - loop-free exact-cover kernel, 4 independent dwordx4 loads in flight
//    per thread (MLP), wave-coalesced at stride 256
//  - nt stores (neutral vs regular, kept from best-measured config)
//  - 8 VGPR -> full occupancy
// Cache-steering probes (nt-store r3, nt-load r5) both neutral: MALL does
// not absorb either stream across replays; traffic is HBM-bound.

typedef float f32x4 __attribute__((ext_vector_type(4)));

__device__ __forceinline__ float quant1(float w) {
    return (w <= -0.5f) ? -0.125f : ((w > 0.5f) ? 0.125f : 0.0f);
}

__device__ __forceinline__ f32x4 quant4(f32x4 v) {
    f32x4 r;
    r.x = quant1(v.x);
    r.y = quant1(v.y);
    r.z = quant1(v.z);
    r.w = quant1(v.w);
    return r;
}

// Each block covers 1024 consecutive float4s (16 KiB). Thread t handles
// base+t, +256, +512, +768 -- wave-coalesced, 4 loads issued back-to-back.
__global__ __launch_bounds__(256) void hcq_v4_u4(const f32x4* __restrict__ in,
                                                 f32x4* __restrict__ out) {
    long long base = (long long)blockIdx.x * 1024 + threadIdx.x;
    f32x4 v0 = in[base];
    f32x4 v1 = in[base + 256];
    f32x4 v2 = in[base + 512];
    f32x4 v3 = in[base + 768];
    f32x4 r0 = quant4(v0);
    f32x4 r1 = quant4(v1);
    f32x4 r2 = quant4(v2);
    f32x4 r3 = quant4(v3);
    __builtin_nontemporal_store(r0, &out[base]);
    __builtin_nontemporal_store(r1, &out[base + 256]);
    __builtin_nontemporal_store(r2, &out[base + 512]);
    __builtin_nontemporal_store(r3, &out[base + 768]);
}

// Remainder: grid-stride over leftover elements (unused at 4096x8192 but
// kept for generality).
__global__ void hcq_tail(const float* __restrict__ in, float* __restrict__ out,
                         int n0, int n) {
    int i = n0 + blockIdx.x * blockDim.x + threadIdx.x;
    int stride = gridDim.x * blockDim.x;
    for (; i < n; i += stride) out[i] = quant1(in[i]);
}

extern "C" void kernel_launch(void* const* d_in, const int* in_sizes, int n_in,
                              void* d_out, int out_size, void* d_ws, size_t ws_size,
                              hipStream_t stream) {
    const float* w = (const float*)d_in[0];
    float* out = (float*)d_out;
    int n = in_sizes[0];

    int n4 = n / 4;
    int chunks = n4 / 1024;              // full 1024-float4 chunks
    if (chunks > 0) {
        hcq_v4_u4<<<chunks, 256, 0, stream>>>((const f32x4*)w, (f32x4*)out);
    }
    int done = chunks * 1024 * 4;        // elements covered
    if (done < n) {
        int rem = n - done;
        int block = 256;
        int grid = (rem + block - 1) / block;
        if (grid > 1024) grid = 1024;
        hcq_tail<<<grid, block, 0, stream>>>(w, out, done, n);
    }
}